// Round 12
// baseline (163.243 us; speedup 1.0000x reference)
//
#include <hip/hip_runtime.h>

#define DEVI __device__ __forceinline__

typedef float fv4 __attribute__((ext_vector_type(4)));
typedef __bf16 bf16x8 __attribute__((ext_vector_type(8)));
typedef unsigned short u16x8 __attribute__((ext_vector_type(8)));
typedef unsigned short u16x4 __attribute__((ext_vector_type(4)));

DEVI fv4 ldv4(const float* p) { return *reinterpret_cast<const fv4*>(p); }
DEVI bf16x8 pkbf(fv4 a, fv4 b) {
  bf16x8 r;
  r[0] = (__bf16)a[0]; r[1] = (__bf16)a[1]; r[2] = (__bf16)a[2]; r[3] = (__bf16)a[3];
  r[4] = (__bf16)b[0]; r[5] = (__bf16)b[1]; r[6] = (__bf16)b[2]; r[7] = (__bf16)b[3];
  return r;
}
DEVI u16x8 b2u(bf16x8 v) { return __builtin_bit_cast(u16x8, v); }
DEVI bf16x8 asbf(u16x8 u) { return __builtin_bit_cast(bf16x8, u); }
DEVI unsigned short bfbits(float x) { __bf16 v = (__bf16)x; return __builtin_bit_cast(unsigned short, v); }
DEVI fv4 MFMA16(bf16x8 a, bf16x8 b, fv4 c) {
  return __builtin_amdgcn_mfma_f32_16x16x32_bf16(a, b, c, 0, 0, 0);
}
// fast silu: x * rcp(1 + exp2(-x*log2e)) -- 5 VALU ops, correct limits at +/-inf
DEVI float siluf(float x) {
  float e = __builtin_amdgcn_exp2f(x * -1.44269504f);
  return x * __builtin_amdgcn_rcpf(1.f + e);
}
DEVI fv4 glu4(fv4 x, fv4 y) {
  fv4 r;
#pragma unroll
  for (int j = 0; j < 4; ++j) r[j] = siluf(x[j]) * y[j];
  return r;
}
// LIGHT barrier: waits only LDS ops (lgkmcnt), then raw s_barrier. Does NOT drain vmcnt.
DEVI void lbar() {
  asm volatile("s_waitcnt lgkmcnt(0)" ::: "memory");
  __builtin_amdgcn_s_barrier();
}
// u16 index into a [rows][384] u16 LDS tile, 16B-unit XOR swizzle on (row&7)
DEVI int swz(int row, int k) {
  int unit = k >> 3;
  int phys = (unit & ~7) | ((unit ^ row) & 7);
  return row * 384 + (phys << 3) + (k & 7);
}

// ---------------- adaLN modulation
__global__ __launch_bounds__(256)
void k_ada(const float* __restrict__ temb, const float* __restrict__ W_ada,
           const float* __restrict__ b_ada, float* __restrict__ ada) {
  __shared__ float sm[256];
  const int b = blockIdx.x / 6;
  const int r = (blockIdx.x % 6) * 256 + threadIdx.x;
  sm[threadIdx.x] = siluf(temb[b * 256 + threadIdx.x]);
  __syncthreads();
  float s = b_ada[r];
  const float* wr = W_ada + (size_t)r * 256;
  for (int k = 0; k < 256; ++k) s += sm[k] * wr[k];
  ada[b * 1536 + r] = s;
}

// ---------------- LN(x*mask) then modulate
__global__ __launch_bounds__(256)
void k_xnorm(const float* __restrict__ xin, const float* __restrict__ mask,
             const float* __restrict__ ada, int shift_off, int scale_off,
             float* __restrict__ out) {
  const int row = blockIdx.x;
  const int b = row / 384;
  const int t = threadIdx.x;
  const float m = mask[row];
  const float v = xin[(size_t)row * 256 + t] * m;
  float s = v, ss = v * v;
#pragma unroll
  for (int o = 1; o < 64; o <<= 1) { s += __shfl_xor(s, o); ss += __shfl_xor(ss, o); }
  __shared__ float red[8];
  const int wid = t >> 6;
  if ((t & 63) == 0) { red[wid] = s; red[4 + wid] = ss; }
  __syncthreads();
  s = red[0] + red[1] + red[2] + red[3];
  ss = red[4] + red[5] + red[6] + red[7];
  const float mean = s * (1.f / 256.f);
  const float var = ss * (1.f / 256.f) - mean * mean;
  const float rs = rsqrtf(var + 1e-6f);
  out[(size_t)row * 256 + t] =
      (v - mean) * rs * (1.f + ada[b * 1536 + scale_off + t]) + ada[b * 1536 + shift_off + t];
}

// ---------------- generic bf16 MFMA GEMM, 64x64 tile (light barriers in K-loop)
// EPI: 0 none; 1 +bscale*bias[col]; 2 res+gate*acc; 3 (res+gate*acc)*mask;
//      7 dual store: virtual N=512 over B-row (r&255), K-slice (r>>8)*256;
//        col<256 -> C row-major (P); col>=256 -> res chunk-tiled (Qc)
// AMODE: 0 plain A; 1 GLU(A[row][c], A[row][1024+c]); 2 A + res (second partial buffer)
template <int EPI, int AMODE>
__global__ __launch_bounds__(256)
void k_gemm(const float* __restrict__ A, int lda,
            const float* __restrict__ B, int ldb, int koff, int K,
            float* __restrict__ C, int ldc,
            const float* __restrict__ bias, float bscale,
            const float* __restrict__ res,
            const float* __restrict__ ada, int gate_off,
            const float* __restrict__ mask) {
  __shared__ __align__(16) unsigned short As[64 * 64];
  __shared__ __align__(16) unsigned short Bs[64 * 64];
  const int t = threadIdx.x, lane = t & 63, w = t >> 6;
  const int bn0 = blockIdx.x * 64, bm0 = blockIdx.y * 64;
  const int qr = (w >> 1) * 32, qc = (w & 1) * 32;
  const int g = lane >> 4, c = lane & 15;
  const int srow = t >> 2;
  const int so = (t & 3) * 2;
  const int o0 = so ^ (srow & 7), o1 = (so + 1) ^ (srow & 7);
  unsigned short* aw0 = As + srow * 64 + o0 * 8;
  unsigned short* aw1 = As + srow * 64 + o1 * 8;
  unsigned short* bw0 = Bs + srow * 64 + o0 * 8;
  unsigned short* bw1 = Bs + srow * 64 + o1 * 8;
  const float* ag = A + (size_t)(bm0 + srow) * lda + so * 8;
  const int vrow = bn0 + srow;
  const float* bg;
  if constexpr (EPI == 7)
    bg = B + (size_t)(vrow & 255) * ldb + (vrow >> 8) * 256 + so * 8;
  else
    bg = B + (size_t)vrow * ldb + koff + so * 8;
  const float* a2g = nullptr;
  if constexpr (AMODE == 2) a2g = res + ((size_t)(bm0 + srow) * lda + so * 8);
  fv4 a0 = ldv4(ag), a1 = ldv4(ag + 4), a2 = ldv4(ag + 8), a3 = ldv4(ag + 12);
  fv4 x0, x1, x2, x3;
  if constexpr (AMODE == 1) {
    x0 = ldv4(ag + 1024); x1 = ldv4(ag + 1028); x2 = ldv4(ag + 1032); x3 = ldv4(ag + 1036);
  }
  if constexpr (AMODE == 2) {
    x0 = ldv4(a2g); x1 = ldv4(a2g + 4); x2 = ldv4(a2g + 8); x3 = ldv4(a2g + 12);
  }
  fv4 c0 = ldv4(bg), c1 = ldv4(bg + 4), c2 = ldv4(bg + 8), c3 = ldv4(bg + 12);
  fv4 acc[2][2] = {};
  for (int k0 = 0; k0 < K; k0 += 64) {
    lbar();
    if constexpr (AMODE == 1) {
      *reinterpret_cast<u16x8*>(aw0) = b2u(pkbf(glu4(a0, x0), glu4(a1, x1)));
      *reinterpret_cast<u16x8*>(aw1) = b2u(pkbf(glu4(a2, x2), glu4(a3, x3)));
    } else if constexpr (AMODE == 2) {
      *reinterpret_cast<u16x8*>(aw0) = b2u(pkbf(a0 + x0, a1 + x1));
      *reinterpret_cast<u16x8*>(aw1) = b2u(pkbf(a2 + x2, a3 + x3));
    } else {
      *reinterpret_cast<u16x8*>(aw0) = b2u(pkbf(a0, a1));
      *reinterpret_cast<u16x8*>(aw1) = b2u(pkbf(a2, a3));
    }
    *reinterpret_cast<u16x8*>(bw0) = b2u(pkbf(c0, c1));
    *reinterpret_cast<u16x8*>(bw1) = b2u(pkbf(c2, c3));
    lbar();
    if (k0 + 64 < K) {
      ag += 64; bg += 64;
      a0 = ldv4(ag); a1 = ldv4(ag + 4); a2 = ldv4(ag + 8); a3 = ldv4(ag + 12);
      if constexpr (AMODE == 1) {
        x0 = ldv4(ag + 1024); x1 = ldv4(ag + 1028); x2 = ldv4(ag + 1032); x3 = ldv4(ag + 1036);
      }
      if constexpr (AMODE == 2) {
        a2g += 64;
        x0 = ldv4(a2g); x1 = ldv4(a2g + 4); x2 = ldv4(a2g + 8); x3 = ldv4(a2g + 12);
      }
      c0 = ldv4(bg); c1 = ldv4(bg + 4); c2 = ldv4(bg + 8); c3 = ldv4(bg + 12);
    }
#pragma unroll
    for (int kk = 0; kk < 2; ++kk) {
      bf16x8 af[2], bf[2];
#pragma unroll
      for (int mi = 0; mi < 2; ++mi) {
        int row = qr + mi * 16 + c;
        int oct = (kk * 4 + g) ^ (row & 7);
        af[mi] = asbf(*reinterpret_cast<const u16x8*>(As + row * 64 + oct * 8));
      }
#pragma unroll
      for (int ni = 0; ni < 2; ++ni) {
        int row = qc + ni * 16 + c;
        int oct = (kk * 4 + g) ^ (row & 7);
        bf[ni] = asbf(*reinterpret_cast<const u16x8*>(Bs + row * 64 + oct * 8));
      }
#pragma unroll
      for (int mi = 0; mi < 2; ++mi)
#pragma unroll
        for (int ni = 0; ni < 2; ++ni)
          acc[mi][ni] = MFMA16(af[mi], bf[ni], acc[mi][ni]);
    }
  }
#pragma unroll
  for (int mi = 0; mi < 2; ++mi)
#pragma unroll
    for (int ni = 0; ni < 2; ++ni)
#pragma unroll
      for (int r = 0; r < 4; ++r) {
        int row = bm0 + qr + mi * 16 + g * 4 + r;
        int col = bn0 + qc + ni * 16 + c;
        float v = acc[mi][ni][r];
        if constexpr (EPI == 7) {
          if (col < 256) C[(size_t)row * ldc + col] = v;
          else ((float*)res)[(((size_t)(row >> 4) * 256 + (col - 256)) << 4) + (row & 15)] = v;
        } else {
          if constexpr (EPI == 1) v += bscale * bias[col];
          if constexpr (EPI == 2) v = res[(size_t)row * 256 + col] + ada[(row / 384) * 1536 + gate_off + col] * v;
          if constexpr (EPI == 3) v = (res[(size_t)row * 256 + col] + ada[(row / 384) * 1536 + gate_off + col] * v) * mask[row];
          C[(size_t)row * ldc + col] = v;
        }
      }
}

// ---------------- edge message kernel v8: BK=32 per barrier interval. 512 thr / 8 waves,
// shared 32x128 j-chunk in LDS (2 buffers, 16 KB). 6 intervals/block (vs 12): each has
// 8 ds_read_b128 + 16 MFMA + ~100 VALU per wave -- double the straggler-fillable work
// per sync. Per thread per interval: 2 dwordx4 dist loads + 1 pack + 1 ds_write_b128.
// dist AND qv/em prefetched one full interval ahead (X/Y ping-pong, named regs).
// Light barriers (lgkmcnt-only). P+Q folded into MFMA acc-init.
__global__ __launch_bounds__(512, 3)
void k_edge(const float* __restrict__ dist, const float* __restrict__ emask,
            const float* __restrict__ Wfe1, const float* __restrict__ bfe1,
            const float* __restrict__ P, const float* __restrict__ Qc,
            float* __restrict__ S0, float* __restrict__ S1) {
  const int blk = blockIdx.x, jh = blockIdx.y;
  const int b = blk / 384, i = blk - b * 384;
  const int t = threadIdx.x, lane = t & 63, w = t >> 6;  // w in 0..7
  const int g = lane >> 4, c = lane & 15;
  __shared__ __align__(16) unsigned short Al[2][32 * 128];  // 16 KB

  // B-fragments: wave w covers h-tiles ht=0,1 at h = w*32 + ht*16 + c
  bf16x8 Bf[2][4];
  float Pl[2], bl[2], Ss[2] = {0.f, 0.f};
#pragma unroll
  for (int ht = 0; ht < 2; ++ht) {
    const int h = w * 32 + ht * 16 + c;
    const float* wp = Wfe1 + (size_t)h * 640 + 512 + g * 8;
#pragma unroll
    for (int ks = 0; ks < 4; ++ks)
      Bf[ht][ks] = pkbf(ldv4(wp + ks * 32), ldv4(wp + ks * 32 + 4));
    Pl[ht] = P[(size_t)(b * 384 + i) * 256 + h];
    bl[ht] = bfe1[h];
  }
  const float* dbase = dist + (size_t)(b * 384 + i) * 49152 + (size_t)jh * 24576;
  const float* embase = emask + (size_t)(b * 384 + i) * 384 + jh * 192;
  const int jcb = b * 24 + jh * 12;   // base 16-row chunk index in Qc
  const int h0 = w * 32 + c, h1 = h0 + 16;

  // staging geometry: thread covers row = t>>4 (0..31), unit u = t&15 (8 floats)
  const int srow = t >> 4, su = t & 15;
  const int sphys = (su & 8) | ((su ^ (srow & 7)) & 7);
  const int soff = srow * 128 + sphys * 8;
  const float* sg = dbase + srow * 128 + su * 8;

  fv4 rX0, rX1, rY0, rY1;
  fv4 qvX0, qvX1, qvX2, qvX3, qvY0, qvY1, qvY2, qvY3;
  fv4 emX0, emX1, emY0, emY1;

  // prologue: stage interval 0, prefetch interval-1 dist + interval-0 qv/em
  {
    fv4 d0 = ldv4(sg), d1 = ldv4(sg + 4);
    rX0 = ldv4(sg + 4096); rX1 = ldv4(sg + 4096 + 4);
    {
      const size_t jc = (size_t)jcb;
      qvX0 = ldv4(Qc + ((jc * 256 + h0) << 4) + g * 4);
      qvX1 = ldv4(Qc + ((jc * 256 + h1) << 4) + g * 4);
      qvX2 = ldv4(Qc + (((jc + 1) * 256 + h0) << 4) + g * 4);
      qvX3 = ldv4(Qc + (((jc + 1) * 256 + h1) << 4) + g * 4);
    }
    emX0 = ldv4(embase + g * 4);
    emX1 = ldv4(embase + 16 + g * 4);
    *reinterpret_cast<u16x8*>(&Al[0][soff]) = b2u(pkbf(d0, d1));
  }
  lbar();

#pragma unroll 1
  for (int p = 0; p < 3; ++p) {
    // ---- interval cl = 2p: compute Al[0]; write Al[1] (interval cl+1 from rX);
    //      prefetch dist cl+2 -> rY, qv/em cl+1 -> Y
    {
      const int cl = 2 * p;
      if (cl <= 4) *reinterpret_cast<u16x8*>(&Al[1][soff]) = b2u(pkbf(rX0, rX1));
      if (cl <= 3) {
        rY0 = ldv4(sg + (size_t)(cl + 2) * 4096);
        rY1 = ldv4(sg + (size_t)(cl + 2) * 4096 + 4);
      }
      if (cl <= 4) {
        const size_t jc = (size_t)(jcb + (cl + 1) * 2);
        qvY0 = ldv4(Qc + ((jc * 256 + h0) << 4) + g * 4);
        qvY1 = ldv4(Qc + ((jc * 256 + h1) << 4) + g * 4);
        qvY2 = ldv4(Qc + (((jc + 1) * 256 + h0) << 4) + g * 4);
        qvY3 = ldv4(Qc + (((jc + 1) * 256 + h1) << 4) + g * 4);
        emY0 = ldv4(embase + (cl + 1) * 32 + g * 4);
        emY1 = ldv4(embase + (cl + 1) * 32 + 16 + g * 4);
      }
      fv4 a00, a01, a10, a11;
#pragma unroll
      for (int r = 0; r < 4; ++r) {
        a00[r] = Pl[0] + qvX0[r]; a01[r] = Pl[1] + qvX1[r];
        a10[r] = Pl[0] + qvX2[r]; a11[r] = Pl[1] + qvX3[r];
      }
#pragma unroll
      for (int ks = 0; ks < 4; ++ks) {
        const int u = ks * 4 + g;
        const int phys = (u & 8) | ((u ^ (c & 7)) & 7);
        bf16x8 af0 = asbf(*reinterpret_cast<const u16x8*>(&Al[0][c * 128 + phys * 8]));
        bf16x8 af1 = asbf(*reinterpret_cast<const u16x8*>(&Al[0][(16 + c) * 128 + phys * 8]));
        a00 = MFMA16(af0, Bf[0][ks], a00); a01 = MFMA16(af0, Bf[1][ks], a01);
        a10 = MFMA16(af1, Bf[0][ks], a10); a11 = MFMA16(af1, Bf[1][ks], a11);
      }
#pragma unroll
      for (int r = 0; r < 4; ++r) {
        Ss[0] += siluf(emX0[r] * a00[r] + bl[0]);
        Ss[1] += siluf(emX0[r] * a01[r] + bl[1]);
        Ss[0] += siluf(emX1[r] * a10[r] + bl[0]);
        Ss[1] += siluf(emX1[r] * a11[r] + bl[1]);
      }
      lbar();
    }
    // ---- interval cl = 2p+1: compute Al[1]; write Al[0] (interval cl+1 from rY);
    //      prefetch dist cl+2 -> rX, qv/em cl+1 -> X
    {
      const int cl = 2 * p + 1;
      if (cl <= 4) *reinterpret_cast<u16x8*>(&Al[0][soff]) = b2u(pkbf(rY0, rY1));
      if (cl <= 3) {
        rX0 = ldv4(sg + (size_t)(cl + 2) * 4096);
        rX1 = ldv4(sg + (size_t)(cl + 2) * 4096 + 4);
      }
      if (cl <= 4) {
        const size_t jc = (size_t)(jcb + (cl + 1) * 2);
        qvX0 = ldv4(Qc + ((jc * 256 + h0) << 4) + g * 4);
        qvX1 = ldv4(Qc + ((jc * 256 + h1) << 4) + g * 4);
        qvX2 = ldv4(Qc + (((jc + 1) * 256 + h0) << 4) + g * 4);
        qvX3 = ldv4(Qc + (((jc + 1) * 256 + h1) << 4) + g * 4);
        emX0 = ldv4(embase + (cl + 1) * 32 + g * 4);
        emX1 = ldv4(embase + (cl + 1) * 32 + 16 + g * 4);
      }
      fv4 a00, a01, a10, a11;
#pragma unroll
      for (int r = 0; r < 4; ++r) {
        a00[r] = Pl[0] + qvY0[r]; a01[r] = Pl[1] + qvY1[r];
        a10[r] = Pl[0] + qvY2[r]; a11[r] = Pl[1] + qvY3[r];
      }
#pragma unroll
      for (int ks = 0; ks < 4; ++ks) {
        const int u = ks * 4 + g;
        const int phys = (u & 8) | ((u ^ (c & 7)) & 7);
        bf16x8 af0 = asbf(*reinterpret_cast<const u16x8*>(&Al[1][c * 128 + phys * 8]));
        bf16x8 af1 = asbf(*reinterpret_cast<const u16x8*>(&Al[1][(16 + c) * 128 + phys * 8]));
        a00 = MFMA16(af0, Bf[0][ks], a00); a01 = MFMA16(af0, Bf[1][ks], a01);
        a10 = MFMA16(af1, Bf[0][ks], a10); a11 = MFMA16(af1, Bf[1][ks], a11);
      }
#pragma unroll
      for (int r = 0; r < 4; ++r) {
        Ss[0] += siluf(emY0[r] * a00[r] + bl[0]);
        Ss[1] += siluf(emY0[r] * a01[r] + bl[1]);
        Ss[0] += siluf(emY1[r] * a10[r] + bl[0]);
        Ss[1] += siluf(emY1[r] * a11[r] + bl[1]);
      }
      lbar();
    }
  }
  float* Sp = jh ? S1 : S0;
#pragma unroll
  for (int ht = 0; ht < 2; ++ht) {
    float s = Ss[ht];
    s += __shfl_xor(s, 16);
    s += __shfl_xor(s, 32);
    if (g == 0) Sp[(size_t)(b * 384 + i) * 256 + w * 32 + ht * 16 + c] = s;
  }
}

// ---------------- LN(Q*mask), LN(K*mask)
__global__ __launch_bounds__(256)
void k_lnqk(const float* __restrict__ qkv, const float* __restrict__ mask,
            float* __restrict__ Qn, float* __restrict__ Kn) {
  const int row = blockIdx.x, t = threadIdx.x;
  const float m = mask[row];
  const float q = qkv[(size_t)row * 768 + t] * m;
  const float k = qkv[(size_t)row * 768 + 256 + t] * m;
  float sq = q, sqq = q * q, sk = k, skk = k * k;
#pragma unroll
  for (int o = 1; o < 64; o <<= 1) {
    sq += __shfl_xor(sq, o); sqq += __shfl_xor(sqq, o);
    sk += __shfl_xor(sk, o); skk += __shfl_xor(skk, o);
  }
  __shared__ float red[16];
  const int wid = t >> 6;
  if ((t & 63) == 0) { red[wid] = sq; red[4 + wid] = sqq; red[8 + wid] = sk; red[12 + wid] = skk; }
  __syncthreads();
  sq = red[0] + red[1] + red[2] + red[3];
  sqq = red[4] + red[5] + red[6] + red[7];
  sk = red[8] + red[9] + red[10] + red[11];
  skk = red[12] + red[13] + red[14] + red[15];
  const float mq = sq * (1.f / 256.f), vq = sqq * (1.f / 256.f) - mq * mq;
  const float mk = sk * (1.f / 256.f), vk = skk * (1.f / 256.f) - mk * mk;
  Qn[(size_t)row * 256 + t] = (q - mq) * rsqrtf(vq + 1e-6f);
  Kn[(size_t)row * 256 + t] = (k - mk) * rsqrtf(vk + 1e-6f);
}

// ---------------- MFMA attention: block = 16 q-rows x (b,h); 4 waves split k-range
__global__ __launch_bounds__(256)
void k_attn(const float* __restrict__ Qn, const float* __restrict__ Kn,
            const float* __restrict__ qkv, const float* __restrict__ mask,
            float* __restrict__ ao) {
  const int bh = blockIdx.y, b = bh >> 3, h = bh & 7;
  const int qg = blockIdx.x;
  const int t = threadIdx.x, lane = t & 63, w = t >> 6;
  const int g = lane >> 4, c = lane & 15;
  __shared__ __align__(16) unsigned short Vt[32 * 384];
  __shared__ __align__(16) unsigned short pl[16 * 384];
  __shared__ float outp[4][16][32];
  __shared__ float redm[4][16], reds[4][16];
  {
    const int d0 = (t & 7) * 4;
    const int kp = t >> 3;
#pragma unroll
    for (int pass = 0; pass < 6; ++pass) {
      int k = pass * 64 + kp * 2;
      fv4 v0 = ldv4(qkv + (size_t)(b * 384 + k) * 768 + 512 + h * 32 + d0);
      fv4 v1 = ldv4(qkv + (size_t)(b * 384 + k + 1) * 768 + 512 + h * 32 + d0);
#pragma unroll
      for (int j = 0; j < 4; ++j) {
        int d = d0 + j;
        unsigned int pr = (unsigned int)bfbits(v0[j]) | ((unsigned int)bfbits(v1[j]) << 16);
        *reinterpret_cast<unsigned int*>(&Vt[swz(d, k)]) = pr;
      }
    }
  }
  bf16x8 qf;
  {
    const float* qp = Qn + (size_t)(b * 384 + qg * 16 + c) * 256 + h * 32 + g * 8;
    qf = pkbf(ldv4(qp), ldv4(qp + 4));
  }
  fv4 sc[6];
#pragma unroll
  for (int kb = 0; kb < 6; ++kb) {
    const float* kp2 = Kn + (size_t)(b * 384 + w * 96 + kb * 16 + c) * 256 + h * 32 + g * 8;
    bf16x8 kf = pkbf(ldv4(kp2), ldv4(kp2 + 4));
    fv4 z = {0.f, 0.f, 0.f, 0.f};
    sc[kb] = MFMA16(qf, kf, z);
  }
  const float rs = 0.1767766952966369f;
  float zz[6][4], mx[4] = {-3e38f, -3e38f, -3e38f, -3e38f};
#pragma unroll
  for (int kb = 0; kb < 6; ++kb) {
    float mb = mask[b * 384 + w * 96 + kb * 16 + c] > 0.f ? 0.f : -1e9f;
#pragma unroll
    for (int r = 0; r < 4; ++r) {
      zz[kb][r] = sc[kb][r] * rs + mb;
      mx[r] = fmaxf(mx[r], zz[kb][r]);
    }
  }
#pragma unroll
  for (int r = 0; r < 4; ++r) {
#pragma unroll
    for (int o = 1; o < 16; o <<= 1) mx[r] = fmaxf(mx[r], __shfl_xor(mx[r], o));
  }
  if (c == 0) {
#pragma unroll
    for (int r = 0; r < 4; ++r) redm[w][g * 4 + r] = mx[r];
  }
  __syncthreads();
  float m4[4], sm[4] = {0.f, 0.f, 0.f, 0.f};
#pragma unroll
  for (int r = 0; r < 4; ++r) {
    int q = g * 4 + r;
    m4[r] = fmaxf(fmaxf(redm[0][q], redm[1][q]), fmaxf(redm[2][q], redm[3][q]));
  }
#pragma unroll
  for (int kb = 0; kb < 6; ++kb) {
    int k = w * 96 + kb * 16 + c;
#pragma unroll
    for (int r = 0; r < 4; ++r) {
      float p = __builtin_amdgcn_exp2f((zz[kb][r] - m4[r]) * 1.44269504f);
      sm[r] += p;
      pl[swz(g * 4 + r, k)] = bfbits(p);
    }
  }
#pragma unroll
  for (int r = 0; r < 4; ++r) {
#pragma unroll
    for (int o = 1; o < 16; o <<= 1) sm[r] += __shfl_xor(sm[r], o);
  }
  if (c == 0) {
#pragma unroll
    for (int r = 0; r < 4; ++r) reds[w][g * 4 + r] = sm[r];
  }
  __syncthreads();
  fv4 oacc[2] = {};
#pragma unroll
  for (int kk = 0; kk < 3; ++kk) {
    int kbase = w * 96 + kk * 32 + g * 8;
    bf16x8 pa = asbf(*reinterpret_cast<const u16x8*>(&pl[swz(c, kbase)]));
#pragma unroll
    for (int db = 0; db < 2; ++db) {
      int d = db * 16 + c;
      bf16x8 vb = asbf(*reinterpret_cast<const u16x8*>(&Vt[swz(d, kbase)]));
      oacc[db] = MFMA16(pa, vb, oacc[db]);
    }
  }
#pragma unroll
  for (int db = 0; db < 2; ++db)
#pragma unroll
    for (int r = 0; r < 4; ++r) outp[w][g * 4 + r][db * 16 + c] = oacc[db][r];
  __syncthreads();
#pragma unroll
  for (int idx = t; idx < 512; idx += 256) {
    int q = idx >> 5, d = idx & 31;
    float v = outp[0][q][d] + outp[1][q][d] + outp[2][q][d] + outp[3][q][d];
    float s = reds[0][q] + reds[1][q] + reds[2][q] + reds[3][q];
    ao[(size_t)(b * 384 + qg * 16 + q) * 256 + h * 32 + d] = v / s;
  }
}

extern "C" void kernel_launch(void* const* d_in, const int* in_sizes, int n_in,
                              void* d_out, int out_size, void* d_ws, size_t ws_size,
                              hipStream_t stream) {
  (void)in_sizes; (void)n_in; (void)out_size; (void)ws_size;
  const float* mask   = (const float*)d_in[0];
  const float* x      = (const float*)d_in[1];
  const float* temb   = (const float*)d_in[2];
  const float* dist   = (const float*)d_in[3];
  const float* emask  = (const float*)d_in[4];
  const float* W_ada  = (const float*)d_in[5];
  const float* b_ada  = (const float*)d_in[6];
  const float* W_fe1  = (const float*)d_in[7];
  const float* b_fe1  = (const float*)d_in[8];
  const float* W_fe2  = (const float*)d_in[9];
  const float* b_fe2  = (const float*)d_in[10];
  const float* W_qkv  = (const float*)d_in[11];
  const float* W_out  = (const float*)d_in[12];
  const float* W_ffn1 = (const float*)d_in[13];
  const float* W_ffn2 = (const float*)d_in[14];
  float* out = (float*)d_out;
  float* ws = (float*)d_ws;

  float* ada   = ws;              // 3072
  float* xattn = ws + 4096;       // 196608
  float* xm    = ws + 200704;     // 196608
  float* xn    = ws + 397312;     // 196608
  float* P     = ws + 593920;     // 196608
  float* Qc    = ws + 790528;     // 196608 (chunk-tiled fp32: [(j>>4)*256+h][j&15])
  float* S0    = ws + 987136;     // 196608 (j-half 0 partial)
  float* xmsg  = ws + 1183744;    // 196608
  float* qkvb  = ws + 1380352;    // 589824
  float* Qn    = ws + 1970176;    // 196608
  float* Kn    = ws + 2166784;    // 196608
  float* aob   = ws + 2363392;    // 196608
  float* S1    = ws + 2363392;    // j-half 1 partial; aliases aob (dead until k_attn)
  float* h12   = ws + 397312;     // 1572864, aliases xn..qkvb (dead by then)

  k_ada<<<12, 256, 0, stream>>>(temb, W_ada, b_ada, ada);
  k_xnorm<<<768, 256, 0, stream>>>(x, mask, ada, 0, 256, xn);
  // merged: P (cols 0..255) + Qc (cols 256..511, chunk-tiled via res) in one launch
  k_gemm<7, 0><<<dim3(8, 12), 256, 0, stream>>>(xn, 256, W_fe1, 640, 0, 256, P, 256,
                                                nullptr, 0.f, Qc, nullptr, 0, nullptr);
  k_edge<<<dim3(768, 2), 512, 0, stream>>>(dist, emask, W_fe1, b_fe1, P, Qc, S0, S1);
  // x_msg = (S0+S1) @ W_fe2^T + 384*b_fe2   (AMODE=2 adds res=S1 rows into A)
  k_gemm<1, 2><<<dim3(4, 12), 256, 0, stream>>>(S0, 256, W_fe2, 256, 0, 256, xmsg, 256,
                                                b_fe2, 384.f, S1, nullptr, 0, nullptr);
  k_gemm<0, 0><<<dim3(12, 12), 256, 0, stream>>>(xmsg, 256, W_qkv, 256, 0, 256, qkvb, 768,
                                                 nullptr, 0.f, nullptr, nullptr, 0, nullptr);
  k_lnqk<<<768, 256, 0, stream>>>(qkvb, mask, Qn, Kn);
  k_attn<<<dim3(24, 16), 256, 0, stream>>>(Qn, Kn, qkvb, mask, aob);
  k_gemm<2, 0><<<dim3(4, 12), 256, 0, stream>>>(aob, 256, W_out, 256, 0, 256, xattn, 256,
                                                nullptr, 0.f, x, ada, 512, nullptr);
  k_xnorm<<<768, 256, 0, stream>>>(xattn, mask, ada, 768, 1024, xm);
  k_gemm<0, 0><<<dim3(32, 12), 256, 0, stream>>>(xm, 256, W_ffn1, 256, 0, 256, h12, 2048,
                                                 nullptr, 0.f, nullptr, nullptr, 0, nullptr);
  k_gemm<3, 1><<<dim3(4, 12), 256, 0, stream>>>(h12, 2048, W_ffn2, 1024, 0, 1024, out, 256,
                                                nullptr, 0.f, xattn, ada, 1280, mask);
}

// Round 13
// 141.879 us; speedup vs baseline: 1.1506x; 1.1506x over previous
//
#include <hip/hip_runtime.h>

#define DEVI __device__ __forceinline__

typedef float fv4 __attribute__((ext_vector_type(4)));
typedef __bf16 bf16x8 __attribute__((ext_vector_type(8)));
typedef unsigned short u16x8 __attribute__((ext_vector_type(8)));
typedef unsigned short u16x4 __attribute__((ext_vector_type(4)));

DEVI fv4 ldv4(const float* p) { return *reinterpret_cast<const fv4*>(p); }
DEVI bf16x8 pkbf(fv4 a, fv4 b) {
  bf16x8 r;
  r[0] = (__bf16)a[0]; r[1] = (__bf16)a[1]; r[2] = (__bf16)a[2]; r[3] = (__bf16)a[3];
  r[4] = (__bf16)b[0]; r[5] = (__bf16)b[1]; r[6] = (__bf16)b[2]; r[7] = (__bf16)b[3];
  return r;
}
DEVI u16x8 b2u(bf16x8 v) { return __builtin_bit_cast(u16x8, v); }
DEVI bf16x8 asbf(u16x8 u) { return __builtin_bit_cast(bf16x8, u); }
DEVI unsigned short bfbits(float x) { __bf16 v = (__bf16)x; return __builtin_bit_cast(unsigned short, v); }
DEVI u16x4 pk4(fv4 a) {
  u16x4 u;
  u[0] = bfbits(a[0]); u[1] = bfbits(a[1]); u[2] = bfbits(a[2]); u[3] = bfbits(a[3]);
  return u;
}
DEVI fv4 MFMA16(bf16x8 a, bf16x8 b, fv4 c) {
  return __builtin_amdgcn_mfma_f32_16x16x32_bf16(a, b, c, 0, 0, 0);
}
// fast silu: x * rcp(1 + exp2(-x*log2e)) -- 5 VALU ops, correct limits at +/-inf
DEVI float siluf(float x) {
  float e = __builtin_amdgcn_exp2f(x * -1.44269504f);
  return x * __builtin_amdgcn_rcpf(1.f + e);
}
DEVI fv4 glu4(fv4 x, fv4 y) {
  fv4 r;
#pragma unroll
  for (int j = 0; j < 4; ++j) r[j] = siluf(x[j]) * y[j];
  return r;
}
// LIGHT barrier: waits only LDS ops (lgkmcnt), then raw s_barrier. Does NOT drain vmcnt.
DEVI void lbar() {
  asm volatile("s_waitcnt lgkmcnt(0)" ::: "memory");
  __builtin_amdgcn_s_barrier();
}
// u16 index into a [rows][384] u16 LDS tile, 16B-unit XOR swizzle on (row&7)
DEVI int swz(int row, int k) {
  int unit = k >> 3;
  int phys = (unit & ~7) | ((unit ^ row) & 7);
  return row * 384 + (phys << 3) + (k & 7);
}

// ---------------- adaLN modulation
__global__ __launch_bounds__(256)
void k_ada(const float* __restrict__ temb, const float* __restrict__ W_ada,
           const float* __restrict__ b_ada, float* __restrict__ ada) {
  __shared__ float sm[256];
  const int b = blockIdx.x / 6;
  const int r = (blockIdx.x % 6) * 256 + threadIdx.x;
  sm[threadIdx.x] = siluf(temb[b * 256 + threadIdx.x]);
  __syncthreads();
  float s = b_ada[r];
  const float* wr = W_ada + (size_t)r * 256;
  for (int k = 0; k < 256; ++k) s += sm[k] * wr[k];
  ada[b * 1536 + r] = s;
}

// ---------------- LN(x*mask) then modulate
__global__ __launch_bounds__(256)
void k_xnorm(const float* __restrict__ xin, const float* __restrict__ mask,
             const float* __restrict__ ada, int shift_off, int scale_off,
             float* __restrict__ out) {
  const int row = blockIdx.x;
  const int b = row / 384;
  const int t = threadIdx.x;
  const float m = mask[row];
  const float v = xin[(size_t)row * 256 + t] * m;
  float s = v, ss = v * v;
#pragma unroll
  for (int o = 1; o < 64; o <<= 1) { s += __shfl_xor(s, o); ss += __shfl_xor(ss, o); }
  __shared__ float red[8];
  const int wid = t >> 6;
  if ((t & 63) == 0) { red[wid] = s; red[4 + wid] = ss; }
  __syncthreads();
  s = red[0] + red[1] + red[2] + red[3];
  ss = red[4] + red[5] + red[6] + red[7];
  const float mean = s * (1.f / 256.f);
  const float var = ss * (1.f / 256.f) - mean * mean;
  const float rs = rsqrtf(var + 1e-6f);
  out[(size_t)row * 256 + t] =
      (v - mean) * rs * (1.f + ada[b * 1536 + scale_off + t]) + ada[b * 1536 + shift_off + t];
}

// ---------------- generic bf16 MFMA GEMM, 64x64 tile (light barriers in K-loop)
// EPI: 0 none; 1 +bscale*bias[col]; 2 res+gate*acc; 3 (res+gate*acc)*mask;
//      7 dual store: virtual N=512 over B-row (r&255), K-slice (r>>8)*256;
//        col<256 -> C row-major (P); col>=256 -> res = Qx lane-exact layout:
//        Qx[((chunk*8 + w)*64 + g*16 + c)*8 + ht*4 + r] where chunk=row>>4,
//        g=(row>>2)&3, r=row&3, w=cq>>5, ht=(cq>>4)&1, c=cq&15 (cq=col-256)
// AMODE: 0 plain A; 1 GLU(A[row][c], A[row][1024+c]); 2 A + res (second partial buffer)
template <int EPI, int AMODE>
__global__ __launch_bounds__(256)
void k_gemm(const float* __restrict__ A, int lda,
            const float* __restrict__ B, int ldb, int koff, int K,
            float* __restrict__ C, int ldc,
            const float* __restrict__ bias, float bscale,
            const float* __restrict__ res,
            const float* __restrict__ ada, int gate_off,
            const float* __restrict__ mask) {
  __shared__ __align__(16) unsigned short As[64 * 64];
  __shared__ __align__(16) unsigned short Bs[64 * 64];
  const int t = threadIdx.x, lane = t & 63, w = t >> 6;
  const int bn0 = blockIdx.x * 64, bm0 = blockIdx.y * 64;
  const int qr = (w >> 1) * 32, qc = (w & 1) * 32;
  const int g = lane >> 4, c = lane & 15;
  const int srow = t >> 2;
  const int so = (t & 3) * 2;
  const int o0 = so ^ (srow & 7), o1 = (so + 1) ^ (srow & 7);
  unsigned short* aw0 = As + srow * 64 + o0 * 8;
  unsigned short* aw1 = As + srow * 64 + o1 * 8;
  unsigned short* bw0 = Bs + srow * 64 + o0 * 8;
  unsigned short* bw1 = Bs + srow * 64 + o1 * 8;
  const float* ag = A + (size_t)(bm0 + srow) * lda + so * 8;
  const int vrow = bn0 + srow;
  const float* bg;
  if constexpr (EPI == 7)
    bg = B + (size_t)(vrow & 255) * ldb + (vrow >> 8) * 256 + so * 8;
  else
    bg = B + (size_t)vrow * ldb + koff + so * 8;
  const float* a2g = nullptr;
  if constexpr (AMODE == 2) a2g = res + ((size_t)(bm0 + srow) * lda + so * 8);
  fv4 a0 = ldv4(ag), a1 = ldv4(ag + 4), a2 = ldv4(ag + 8), a3 = ldv4(ag + 12);
  fv4 x0, x1, x2, x3;
  if constexpr (AMODE == 1) {
    x0 = ldv4(ag + 1024); x1 = ldv4(ag + 1028); x2 = ldv4(ag + 1032); x3 = ldv4(ag + 1036);
  }
  if constexpr (AMODE == 2) {
    x0 = ldv4(a2g); x1 = ldv4(a2g + 4); x2 = ldv4(a2g + 8); x3 = ldv4(a2g + 12);
  }
  fv4 c0 = ldv4(bg), c1 = ldv4(bg + 4), c2 = ldv4(bg + 8), c3 = ldv4(bg + 12);
  fv4 acc[2][2] = {};
  for (int k0 = 0; k0 < K; k0 += 64) {
    lbar();
    if constexpr (AMODE == 1) {
      *reinterpret_cast<u16x8*>(aw0) = b2u(pkbf(glu4(a0, x0), glu4(a1, x1)));
      *reinterpret_cast<u16x8*>(aw1) = b2u(pkbf(glu4(a2, x2), glu4(a3, x3)));
    } else if constexpr (AMODE == 2) {
      *reinterpret_cast<u16x8*>(aw0) = b2u(pkbf(a0 + x0, a1 + x1));
      *reinterpret_cast<u16x8*>(aw1) = b2u(pkbf(a2 + x2, a3 + x3));
    } else {
      *reinterpret_cast<u16x8*>(aw0) = b2u(pkbf(a0, a1));
      *reinterpret_cast<u16x8*>(aw1) = b2u(pkbf(a2, a3));
    }
    *reinterpret_cast<u16x8*>(bw0) = b2u(pkbf(c0, c1));
    *reinterpret_cast<u16x8*>(bw1) = b2u(pkbf(c2, c3));
    lbar();
    if (k0 + 64 < K) {
      ag += 64; bg += 64;
      a0 = ldv4(ag); a1 = ldv4(ag + 4); a2 = ldv4(ag + 8); a3 = ldv4(ag + 12);
      if constexpr (AMODE == 1) {
        x0 = ldv4(ag + 1024); x1 = ldv4(ag + 1028); x2 = ldv4(ag + 1032); x3 = ldv4(ag + 1036);
      }
      if constexpr (AMODE == 2) {
        a2g += 64;
        x0 = ldv4(a2g); x1 = ldv4(a2g + 4); x2 = ldv4(a2g + 8); x3 = ldv4(a2g + 12);
      }
      c0 = ldv4(bg); c1 = ldv4(bg + 4); c2 = ldv4(bg + 8); c3 = ldv4(bg + 12);
    }
#pragma unroll
    for (int kk = 0; kk < 2; ++kk) {
      bf16x8 af[2], bf[2];
#pragma unroll
      for (int mi = 0; mi < 2; ++mi) {
        int row = qr + mi * 16 + c;
        int oct = (kk * 4 + g) ^ (row & 7);
        af[mi] = asbf(*reinterpret_cast<const u16x8*>(As + row * 64 + oct * 8));
      }
#pragma unroll
      for (int ni = 0; ni < 2; ++ni) {
        int row = qc + ni * 16 + c;
        int oct = (kk * 4 + g) ^ (row & 7);
        bf[ni] = asbf(*reinterpret_cast<const u16x8*>(Bs + row * 64 + oct * 8));
      }
#pragma unroll
      for (int mi = 0; mi < 2; ++mi)
#pragma unroll
        for (int ni = 0; ni < 2; ++ni)
          acc[mi][ni] = MFMA16(af[mi], bf[ni], acc[mi][ni]);
    }
  }
#pragma unroll
  for (int mi = 0; mi < 2; ++mi)
#pragma unroll
    for (int ni = 0; ni < 2; ++ni)
#pragma unroll
      for (int r = 0; r < 4; ++r) {
        int row = bm0 + qr + mi * 16 + g * 4 + r;
        int col = bn0 + qc + ni * 16 + c;
        float v = acc[mi][ni][r];
        if constexpr (EPI == 7) {
          if (col < 256) {
            C[(size_t)row * ldc + col] = v;
          } else {
            int cq = col - 256;
            size_t idx = (((size_t)(row >> 4) * 8 + (cq >> 5)) * 64 +
                          ((row >> 2) & 3) * 16 + (cq & 15)) * 8 +
                         ((cq >> 4) & 1) * 4 + (row & 3);
            ((float*)res)[idx] = v;
          }
        } else {
          if constexpr (EPI == 1) v += bscale * bias[col];
          if constexpr (EPI == 2) v = res[(size_t)row * 256 + col] + ada[(row / 384) * 1536 + gate_off + col] * v;
          if constexpr (EPI == 3) v = (res[(size_t)row * 256 + col] + ada[(row / 384) * 1536 + gate_off + col] * v) * mask[row];
          C[(size_t)row * ldc + col] = v;
        }
      }
}

// ---------------- edge message kernel (r11 structure + lane-exact Qx): 512 thr / 8 waves,
// SHARED j-chunk in LDS. Per chunk per thread: ONE dwordx4 dist load + one pk4 + one
// ds_write_b64. Waves split h (wave w covers [w*32, w*32+32)). dist 2-deep in regs
// (rX/rY ping-pong), qv/em prefetched 1 chunk ahead. qv load is now ONE fully-coalesced
// 32B/lane read from the lane-exact Qx layout (was a 16-segment gather from chunk-tiled
// Qc -- the 16x L1-transaction amplification on the critical prefetch path).
// Light barriers (lgkmcnt-only, vmcnt prefetches survive). P+Q folded into acc-init.
__global__ __launch_bounds__(512)
void k_edge(const float* __restrict__ dist, const float* __restrict__ emask,
            const float* __restrict__ Wfe1, const float* __restrict__ bfe1,
            const float* __restrict__ P, const float* __restrict__ Qx,
            float* __restrict__ S0, float* __restrict__ S1) {
  const int blk = blockIdx.x, jh = blockIdx.y;
  const int b = blk / 384, i = blk - b * 384;
  const int t = threadIdx.x, lane = t & 63, w = t >> 6;  // w in 0..7
  const int g = lane >> 4, c = lane & 15;
  __shared__ __align__(16) unsigned short Al[2][16 * 128];

  // B-fragments: wave w covers h-tiles ht=0,1 at h = w*32 + ht*16 + c
  bf16x8 Bf[2][4];
  float Pl[2], bl[2], Ss[2] = {0.f, 0.f};
#pragma unroll
  for (int ht = 0; ht < 2; ++ht) {
    const int h = w * 32 + ht * 16 + c;
    const float* wp = Wfe1 + (size_t)h * 640 + 512 + g * 8;
#pragma unroll
    for (int ks = 0; ks < 4; ++ks)
      Bf[ht][ks] = pkbf(ldv4(wp + ks * 32), ldv4(wp + ks * 32 + 4));
    Pl[ht] = P[(size_t)(b * 384 + i) * 256 + h];
    bl[ht] = bfe1[h];
  }
  const float* dbase = dist + (size_t)(b * 384 + i) * 49152 + (size_t)jh * 24576;
  const float* embase = emask + (size_t)(b * 384 + i) * 384 + jh * 192;
  const int jcb = b * 24 + jh * 12;
  // lane-exact Q base: per chunk, this lane's 8 floats live contiguously
  const float* qbase = Qx + (((size_t)jcb * 8 + w) * 64 + lane) * 8;

  // staging geometry: thread t covers row=t>>5 (j in chunk), 4 floats at col 4*(t&31)
  const int srow = t >> 5, kq = t & 31;
  const int sunit = kq >> 1;
  const int sphys = (sunit & 8) | ((sunit ^ (srow & 7)) & 7);
  const int soff = srow * 128 + sphys * 8 + (kq & 1) * 4;

  fv4 rX, rY, qvX0, qvX1, qvY0, qvY1, emX, emY;
  // prologue: stage chunk0, prefetch chunk1 + qv/em for chunk0
  {
    fv4 t0 = ldv4(dbase + t * 4);
    *reinterpret_cast<u16x4*>(&Al[0][soff]) = pk4(t0);
  }
  rX = ldv4(dbase + 2048 + t * 4);
  qvX0 = ldv4(qbase);
  qvX1 = ldv4(qbase + 4);
  emX = ldv4(embase + g * 4);
  lbar();

#pragma unroll 1
  for (int p = 0; p < 6; ++p) {
    // ---- iterA: cl = 2p, compute buf0, write buf1 (chunk cl+1 from rX), prefetch into Y
    {
      const int cl = 2 * p;
      if (cl <= 9) rY = ldv4(dbase + (size_t)(cl + 2) * 2048 + t * 4);
      if (cl <= 10) {
        *reinterpret_cast<u16x4*>(&Al[1][soff]) = pk4(rX);
        const float* qp = qbase + (size_t)(cl + 1) * 4096;
        qvY0 = ldv4(qp);
        qvY1 = ldv4(qp + 4);
        emY = ldv4(embase + (cl + 1) * 16 + g * 4);
      }
      fv4 acc0, acc1;
#pragma unroll
      for (int r = 0; r < 4; ++r) { acc0[r] = Pl[0] + qvX0[r]; acc1[r] = Pl[1] + qvX1[r]; }
#pragma unroll
      for (int ks = 0; ks < 4; ++ks) {
        const int u = ks * 4 + g;
        const int phys = (u & 8) | ((u ^ (c & 7)) & 7);
        bf16x8 af = asbf(*reinterpret_cast<const u16x8*>(&Al[0][c * 128 + phys * 8]));
        acc0 = MFMA16(af, Bf[0][ks], acc0);
        acc1 = MFMA16(af, Bf[1][ks], acc1);
      }
#pragma unroll
      for (int r = 0; r < 4; ++r) {
        Ss[0] += siluf(emX[r] * acc0[r] + bl[0]);
        Ss[1] += siluf(emX[r] * acc1[r] + bl[1]);
      }
      lbar();
    }
    // ---- iterB: cl = 2p+1, compute buf1, write buf0 (chunk cl+1 from rY), prefetch into X
    {
      const int cl = 2 * p + 1;
      if (cl <= 9) rX = ldv4(dbase + (size_t)(cl + 2) * 2048 + t * 4);
      if (cl <= 10) {
        *reinterpret_cast<u16x4*>(&Al[0][soff]) = pk4(rY);
        const float* qp = qbase + (size_t)(cl + 1) * 4096;
        qvX0 = ldv4(qp);
        qvX1 = ldv4(qp + 4);
        emX = ldv4(embase + (cl + 1) * 16 + g * 4);
      }
      fv4 acc0, acc1;
#pragma unroll
      for (int r = 0; r < 4; ++r) { acc0[r] = Pl[0] + qvY0[r]; acc1[r] = Pl[1] + qvY1[r]; }
#pragma unroll
      for (int ks = 0; ks < 4; ++ks) {
        const int u = ks * 4 + g;
        const int phys = (u & 8) | ((u ^ (c & 7)) & 7);
        bf16x8 af = asbf(*reinterpret_cast<const u16x8*>(&Al[1][c * 128 + phys * 8]));
        acc0 = MFMA16(af, Bf[0][ks], acc0);
        acc1 = MFMA16(af, Bf[1][ks], acc1);
      }
#pragma unroll
      for (int r = 0; r < 4; ++r) {
        Ss[0] += siluf(emY[r] * acc0[r] + bl[0]);
        Ss[1] += siluf(emY[r] * acc1[r] + bl[1]);
      }
      lbar();
    }
  }
  float* Sp = jh ? S1 : S0;
#pragma unroll
  for (int ht = 0; ht < 2; ++ht) {
    float s = Ss[ht];
    s += __shfl_xor(s, 16);
    s += __shfl_xor(s, 32);
    if (g == 0) Sp[(size_t)(b * 384 + i) * 256 + w * 32 + ht * 16 + c] = s;
  }
}

// ---------------- LN(Q*mask), LN(K*mask)
__global__ __launch_bounds__(256)
void k_lnqk(const float* __restrict__ qkv, const float* __restrict__ mask,
            float* __restrict__ Qn, float* __restrict__ Kn) {
  const int row = blockIdx.x, t = threadIdx.x;
  const float m = mask[row];
  const float q = qkv[(size_t)row * 768 + t] * m;
  const float k = qkv[(size_t)row * 768 + 256 + t] * m;
  float sq = q, sqq = q * q, sk = k, skk = k * k;
#pragma unroll
  for (int o = 1; o < 64; o <<= 1) {
    sq += __shfl_xor(sq, o); sqq += __shfl_xor(sqq, o);
    sk += __shfl_xor(sk, o); skk += __shfl_xor(skk, o);
  }
  __shared__ float red[16];
  const int wid = t >> 6;
  if ((t & 63) == 0) { red[wid] = sq; red[4 + wid] = sqq; red[8 + wid] = sk; red[12 + wid] = skk; }
  __syncthreads();
  sq = red[0] + red[1] + red[2] + red[3];
  sqq = red[4] + red[5] + red[6] + red[7];
  sk = red[8] + red[9] + red[10] + red[11];
  skk = red[12] + red[13] + red[14] + red[15];
  const float mq = sq * (1.f / 256.f), vq = sqq * (1.f / 256.f) - mq * mq;
  const float mk = sk * (1.f / 256.f), vk = skk * (1.f / 256.f) - mk * mk;
  Qn[(size_t)row * 256 + t] = (q - mq) * rsqrtf(vq + 1e-6f);
  Kn[(size_t)row * 256 + t] = (k - mk) * rsqrtf(vk + 1e-6f);
}

// ---------------- MFMA attention: block = 16 q-rows x (b,h); 4 waves split k-range
__global__ __launch_bounds__(256)
void k_attn(const float* __restrict__ Qn, const float* __restrict__ Kn,
            const float* __restrict__ qkv, const float* __restrict__ mask,
            float* __restrict__ ao) {
  const int bh = blockIdx.y, b = bh >> 3, h = bh & 7;
  const int qg = blockIdx.x;
  const int t = threadIdx.x, lane = t & 63, w = t >> 6;
  const int g = lane >> 4, c = lane & 15;
  __shared__ __align__(16) unsigned short Vt[32 * 384];
  __shared__ __align__(16) unsigned short pl[16 * 384];
  __shared__ float outp[4][16][32];
  __shared__ float redm[4][16], reds[4][16];
  {
    const int d0 = (t & 7) * 4;
    const int kp = t >> 3;
#pragma unroll
    for (int pass = 0; pass < 6; ++pass) {
      int k = pass * 64 + kp * 2;
      fv4 v0 = ldv4(qkv + (size_t)(b * 384 + k) * 768 + 512 + h * 32 + d0);
      fv4 v1 = ldv4(qkv + (size_t)(b * 384 + k + 1) * 768 + 512 + h * 32 + d0);
#pragma unroll
      for (int j = 0; j < 4; ++j) {
        int d = d0 + j;
        unsigned int pr = (unsigned int)bfbits(v0[j]) | ((unsigned int)bfbits(v1[j]) << 16);
        *reinterpret_cast<unsigned int*>(&Vt[swz(d, k)]) = pr;
      }
    }
  }
  bf16x8 qf;
  {
    const float* qp = Qn + (size_t)(b * 384 + qg * 16 + c) * 256 + h * 32 + g * 8;
    qf = pkbf(ldv4(qp), ldv4(qp + 4));
  }
  fv4 sc[6];
#pragma unroll
  for (int kb = 0; kb < 6; ++kb) {
    const float* kp2 = Kn + (size_t)(b * 384 + w * 96 + kb * 16 + c) * 256 + h * 32 + g * 8;
    bf16x8 kf = pkbf(ldv4(kp2), ldv4(kp2 + 4));
    fv4 z = {0.f, 0.f, 0.f, 0.f};
    sc[kb] = MFMA16(qf, kf, z);
  }
  const float rs = 0.1767766952966369f;
  float zz[6][4], mx[4] = {-3e38f, -3e38f, -3e38f, -3e38f};
#pragma unroll
  for (int kb = 0; kb < 6; ++kb) {
    float mb = mask[b * 384 + w * 96 + kb * 16 + c] > 0.f ? 0.f : -1e9f;
#pragma unroll
    for (int r = 0; r < 4; ++r) {
      zz[kb][r] = sc[kb][r] * rs + mb;
      mx[r] = fmaxf(mx[r], zz[kb][r]);
    }
  }
#pragma unroll
  for (int r = 0; r < 4; ++r) {
#pragma unroll
    for (int o = 1; o < 16; o <<= 1) mx[r] = fmaxf(mx[r], __shfl_xor(mx[r], o));
  }
  if (c == 0) {
#pragma unroll
    for (int r = 0; r < 4; ++r) redm[w][g * 4 + r] = mx[r];
  }
  __syncthreads();
  float m4[4], sm[4] = {0.f, 0.f, 0.f, 0.f};
#pragma unroll
  for (int r = 0; r < 4; ++r) {
    int q = g * 4 + r;
    m4[r] = fmaxf(fmaxf(redm[0][q], redm[1][q]), fmaxf(redm[2][q], redm[3][q]));
  }
#pragma unroll
  for (int kb = 0; kb < 6; ++kb) {
    int k = w * 96 + kb * 16 + c;
#pragma unroll
    for (int r = 0; r < 4; ++r) {
      float p = __builtin_amdgcn_exp2f((zz[kb][r] - m4[r]) * 1.44269504f);
      sm[r] += p;
      pl[swz(g * 4 + r, k)] = bfbits(p);
    }
  }
#pragma unroll
  for (int r = 0; r < 4; ++r) {
#pragma unroll
    for (int o = 1; o < 16; o <<= 1) sm[r] += __shfl_xor(sm[r], o);
  }
  if (c == 0) {
#pragma unroll
    for (int r = 0; r < 4; ++r) reds[w][g * 4 + r] = sm[r];
  }
  __syncthreads();
  fv4 oacc[2] = {};
#pragma unroll
  for (int kk = 0; kk < 3; ++kk) {
    int kbase = w * 96 + kk * 32 + g * 8;
    bf16x8 pa = asbf(*reinterpret_cast<const u16x8*>(&pl[swz(c, kbase)]));
#pragma unroll
    for (int db = 0; db < 2; ++db) {
      int d = db * 16 + c;
      bf16x8 vb = asbf(*reinterpret_cast<const u16x8*>(&Vt[swz(d, kbase)]));
      oacc[db] = MFMA16(pa, vb, oacc[db]);
    }
  }
#pragma unroll
  for (int db = 0; db < 2; ++db)
#pragma unroll
    for (int r = 0; r < 4; ++r) outp[w][g * 4 + r][db * 16 + c] = oacc[db][r];
  __syncthreads();
#pragma unroll
  for (int idx = t; idx < 512; idx += 256) {
    int q = idx >> 5, d = idx & 31;
    float v = outp[0][q][d] + outp[1][q][d] + outp[2][q][d] + outp[3][q][d];
    float s = reds[0][q] + reds[1][q] + reds[2][q] + reds[3][q];
    ao[(size_t)(b * 384 + qg * 16 + q) * 256 + h * 32 + d] = v / s;
  }
}

extern "C" void kernel_launch(void* const* d_in, const int* in_sizes, int n_in,
                              void* d_out, int out_size, void* d_ws, size_t ws_size,
                              hipStream_t stream) {
  (void)in_sizes; (void)n_in; (void)out_size; (void)ws_size;
  const float* mask   = (const float*)d_in[0];
  const float* x      = (const float*)d_in[1];
  const float* temb   = (const float*)d_in[2];
  const float* dist   = (const float*)d_in[3];
  const float* emask  = (const float*)d_in[4];
  const float* W_ada  = (const float*)d_in[5];
  const float* b_ada  = (const float*)d_in[6];
  const float* W_fe1  = (const float*)d_in[7];
  const float* b_fe1  = (const float*)d_in[8];
  const float* W_fe2  = (const float*)d_in[9];
  const float* b_fe2  = (const float*)d_in[10];
  const float* W_qkv  = (const float*)d_in[11];
  const float* W_out  = (const float*)d_in[12];
  const float* W_ffn1 = (const float*)d_in[13];
  const float* W_ffn2 = (const float*)d_in[14];
  float* out = (float*)d_out;
  float* ws = (float*)d_ws;

  float* ada   = ws;              // 3072
  float* xattn = ws + 4096;       // 196608
  float* xm    = ws + 200704;     // 196608
  float* xn    = ws + 397312;     // 196608
  float* P     = ws + 593920;     // 196608
  float* Qx    = ws + 790528;     // 196608 (lane-exact: [(chunk*8+w)*64+lane][8])
  float* S0    = ws + 987136;     // 196608 (j-half 0 partial)
  float* xmsg  = ws + 1183744;    // 196608
  float* qkvb  = ws + 1380352;    // 589824
  float* Qn    = ws + 1970176;    // 196608
  float* Kn    = ws + 2166784;    // 196608
  float* aob   = ws + 2363392;    // 196608
  float* S1    = ws + 2363392;    // j-half 1 partial; aliases aob (dead until k_attn)
  float* h12   = ws + 397312;     // 1572864, aliases xn..qkvb (dead by then)

  k_ada<<<12, 256, 0, stream>>>(temb, W_ada, b_ada, ada);
  k_xnorm<<<768, 256, 0, stream>>>(x, mask, ada, 0, 256, xn);
  // merged: P (cols 0..255) + Qx (cols 256..511, lane-exact via res) in one launch
  k_gemm<7, 0><<<dim3(8, 12), 256, 0, stream>>>(xn, 256, W_fe1, 640, 0, 256, P, 256,
                                                nullptr, 0.f, Qx, nullptr, 0, nullptr);
  k_edge<<<dim3(768, 2), 512, 0, stream>>>(dist, emask, W_fe1, b_fe1, P, Qx, S0, S1);
  // x_msg = (S0+S1) @ W_fe2^T + 384*b_fe2   (AMODE=2 adds res=S1 rows into A)
  k_gemm<1, 2><<<dim3(4, 12), 256, 0, stream>>>(S0, 256, W_fe2, 256, 0, 256, xmsg, 256,
                                                b_fe2, 384.f, S1, nullptr, 0, nullptr);
  k_gemm<0, 0><<<dim3(12, 12), 256, 0, stream>>>(xmsg, 256, W_qkv, 256, 0, 256, qkvb, 768,
                                                 nullptr, 0.f, nullptr, nullptr, 0, nullptr);
  k_lnqk<<<768, 256, 0, stream>>>(qkvb, mask, Qn, Kn);
  k_attn<<<dim3(24, 16), 256, 0, stream>>>(Qn, Kn, qkvb, mask, aob);
  k_gemm<2, 0><<<dim3(4, 12), 256, 0, stream>>>(aob, 256, W_out, 256, 0, 256, xattn, 256,
                                                nullptr, 0.f, x, ada, 512, nullptr);
  k_xnorm<<<768, 256, 0, stream>>>(xattn, mask, ada, 768, 1024, xm);
  k_gemm<0, 0><<<dim3(32, 12), 256, 0, stream>>>(xm, 256, W_ffn1, 256, 0, 256, h12, 2048,
                                                 nullptr, 0.f, nullptr, nullptr, 0, nullptr);
  k_gemm<3, 1><<<dim3(4, 12), 256, 0, stream>>>(h12, 2048, W_ffn2, 1024, 0, 1024, out, 256,
                                                nullptr, 0.f, xattn, ada, 1280, mask);
}

// Round 14
// 141.546 us; speedup vs baseline: 1.1533x; 1.0024x over previous
//
#include <hip/hip_runtime.h>

#define DEVI __device__ __forceinline__

typedef float fv4 __attribute__((ext_vector_type(4)));
typedef __bf16 bf16x8 __attribute__((ext_vector_type(8)));
typedef unsigned short u16x8 __attribute__((ext_vector_type(8)));
typedef unsigned short u16x4 __attribute__((ext_vector_type(4)));

DEVI fv4 ldv4(const float* p) { return *reinterpret_cast<const fv4*>(p); }
DEVI bf16x8 pkbf(fv4 a, fv4 b) {
  bf16x8 r;
  r[0] = (__bf16)a[0]; r[1] = (__bf16)a[1]; r[2] = (__bf16)a[2]; r[3] = (__bf16)a[3];
  r[4] = (__bf16)b[0]; r[5] = (__bf16)b[1]; r[6] = (__bf16)b[2]; r[7] = (__bf16)b[3];
  return r;
}
DEVI u16x8 b2u(bf16x8 v) { return __builtin_bit_cast(u16x8, v); }
DEVI bf16x8 asbf(u16x8 u) { return __builtin_bit_cast(bf16x8, u); }
DEVI unsigned short bfbits(float x) { __bf16 v = (__bf16)x; return __builtin_bit_cast(unsigned short, v); }
DEVI u16x4 pk4(fv4 a) {
  u16x4 u;
  u[0] = bfbits(a[0]); u[1] = bfbits(a[1]); u[2] = bfbits(a[2]); u[3] = bfbits(a[3]);
  return u;
}
DEVI fv4 MFMA16(bf16x8 a, bf16x8 b, fv4 c) {
  return __builtin_amdgcn_mfma_f32_16x16x32_bf16(a, b, c, 0, 0, 0);
}
// fast silu: x * rcp(1 + exp2(-x*log2e)) -- 5 VALU ops, correct limits at +/-inf
DEVI float siluf(float x) {
  float e = __builtin_amdgcn_exp2f(x * -1.44269504f);
  return x * __builtin_amdgcn_rcpf(1.f + e);
}
DEVI fv4 glu4(fv4 x, fv4 y) {
  fv4 r;
#pragma unroll
  for (int j = 0; j < 4; ++j) r[j] = siluf(x[j]) * y[j];
  return r;
}
// LIGHT barrier: waits only LDS ops (lgkmcnt), then raw s_barrier. Does NOT drain vmcnt.
DEVI void lbar() {
  asm volatile("s_waitcnt lgkmcnt(0)" ::: "memory");
  __builtin_amdgcn_s_barrier();
}
// u16 index into a [rows][384] u16 LDS tile, 16B-unit XOR swizzle on (row&7)
DEVI int swz(int row, int k) {
  int unit = k >> 3;
  int phys = (unit & ~7) | ((unit ^ row) & 7);
  return row * 384 + (phys << 3) + (k & 7);
}

// ---------------- adaLN modulation
__global__ __launch_bounds__(256)
void k_ada(const float* __restrict__ temb, const float* __restrict__ W_ada,
           const float* __restrict__ b_ada, float* __restrict__ ada) {
  __shared__ float sm[256];
  const int b = blockIdx.x / 6;
  const int r = (blockIdx.x % 6) * 256 + threadIdx.x;
  sm[threadIdx.x] = siluf(temb[b * 256 + threadIdx.x]);
  __syncthreads();
  float s = b_ada[r];
  const float* wr = W_ada + (size_t)r * 256;
  for (int k = 0; k < 256; ++k) s += sm[k] * wr[k];
  ada[b * 1536 + r] = s;
}

// ---------------- LN(x*mask) then modulate
__global__ __launch_bounds__(256)
void k_xnorm(const float* __restrict__ xin, const float* __restrict__ mask,
             const float* __restrict__ ada, int shift_off, int scale_off,
             float* __restrict__ out) {
  const int row = blockIdx.x;
  const int b = row / 384;
  const int t = threadIdx.x;
  const float m = mask[row];
  const float v = xin[(size_t)row * 256 + t] * m;
  float s = v, ss = v * v;
#pragma unroll
  for (int o = 1; o < 64; o <<= 1) { s += __shfl_xor(s, o); ss += __shfl_xor(ss, o); }
  __shared__ float red[8];
  const int wid = t >> 6;
  if ((t & 63) == 0) { red[wid] = s; red[4 + wid] = ss; }
  __syncthreads();
  s = red[0] + red[1] + red[2] + red[3];
  ss = red[4] + red[5] + red[6] + red[7];
  const float mean = s * (1.f / 256.f);
  const float var = ss * (1.f / 256.f) - mean * mean;
  const float rs = rsqrtf(var + 1e-6f);
  out[(size_t)row * 256 + t] =
      (v - mean) * rs * (1.f + ada[b * 1536 + scale_off + t]) + ada[b * 1536 + shift_off + t];
}

// ---------------- generic bf16 MFMA GEMM, 64x64 tile (light barriers in K-loop)
// EPI: 0 none; 1 +bscale*bias[col]; 2 res+gate*acc; 3 (res+gate*acc)*mask;
//      7 dual store (P row-major / Qx lane-exact via res);
//      8 plain C store + masked LN partial stats (sum,sumsq per row per 64-col tile)
//        into res: stats[row][16] with entries [bn*2, bn*2+1] for bn=blockIdx.x<8
// AMODE: 0 plain A; 1 GLU(A[row][c], A[row][1024+c]); 2 A + res (second partial buffer)
template <int EPI, int AMODE>
__global__ __launch_bounds__(256)
void k_gemm(const float* __restrict__ A, int lda,
            const float* __restrict__ B, int ldb, int koff, int K,
            float* __restrict__ C, int ldc,
            const float* __restrict__ bias, float bscale,
            const float* __restrict__ res,
            const float* __restrict__ ada, int gate_off,
            const float* __restrict__ mask) {
  __shared__ __align__(16) unsigned short As[64 * 64];
  __shared__ __align__(16) unsigned short Bs[64 * 64];
  const int t = threadIdx.x, lane = t & 63, w = t >> 6;
  const int bn0 = blockIdx.x * 64, bm0 = blockIdx.y * 64;
  const int qr = (w >> 1) * 32, qc = (w & 1) * 32;
  const int g = lane >> 4, c = lane & 15;
  const int srow = t >> 2;
  const int so = (t & 3) * 2;
  const int o0 = so ^ (srow & 7), o1 = (so + 1) ^ (srow & 7);
  unsigned short* aw0 = As + srow * 64 + o0 * 8;
  unsigned short* aw1 = As + srow * 64 + o1 * 8;
  unsigned short* bw0 = Bs + srow * 64 + o0 * 8;
  unsigned short* bw1 = Bs + srow * 64 + o1 * 8;
  const float* ag = A + (size_t)(bm0 + srow) * lda + so * 8;
  const int vrow = bn0 + srow;
  const float* bg;
  if constexpr (EPI == 7)
    bg = B + (size_t)(vrow & 255) * ldb + (vrow >> 8) * 256 + so * 8;
  else
    bg = B + (size_t)vrow * ldb + koff + so * 8;
  const float* a2g = nullptr;
  if constexpr (AMODE == 2) a2g = res + ((size_t)(bm0 + srow) * lda + so * 8);
  fv4 a0 = ldv4(ag), a1 = ldv4(ag + 4), a2 = ldv4(ag + 8), a3 = ldv4(ag + 12);
  fv4 x0, x1, x2, x3;
  if constexpr (AMODE == 1) {
    x0 = ldv4(ag + 1024); x1 = ldv4(ag + 1028); x2 = ldv4(ag + 1032); x3 = ldv4(ag + 1036);
  }
  if constexpr (AMODE == 2) {
    x0 = ldv4(a2g); x1 = ldv4(a2g + 4); x2 = ldv4(a2g + 8); x3 = ldv4(a2g + 12);
  }
  fv4 c0 = ldv4(bg), c1 = ldv4(bg + 4), c2 = ldv4(bg + 8), c3 = ldv4(bg + 12);
  fv4 acc[2][2] = {};
  for (int k0 = 0; k0 < K; k0 += 64) {
    lbar();
    if constexpr (AMODE == 1) {
      *reinterpret_cast<u16x8*>(aw0) = b2u(pkbf(glu4(a0, x0), glu4(a1, x1)));
      *reinterpret_cast<u16x8*>(aw1) = b2u(pkbf(glu4(a2, x2), glu4(a3, x3)));
    } else if constexpr (AMODE == 2) {
      *reinterpret_cast<u16x8*>(aw0) = b2u(pkbf(a0 + x0, a1 + x1));
      *reinterpret_cast<u16x8*>(aw1) = b2u(pkbf(a2 + x2, a3 + x3));
    } else {
      *reinterpret_cast<u16x8*>(aw0) = b2u(pkbf(a0, a1));
      *reinterpret_cast<u16x8*>(aw1) = b2u(pkbf(a2, a3));
    }
    *reinterpret_cast<u16x8*>(bw0) = b2u(pkbf(c0, c1));
    *reinterpret_cast<u16x8*>(bw1) = b2u(pkbf(c2, c3));
    lbar();
    if (k0 + 64 < K) {
      ag += 64; bg += 64;
      a0 = ldv4(ag); a1 = ldv4(ag + 4); a2 = ldv4(ag + 8); a3 = ldv4(ag + 12);
      if constexpr (AMODE == 1) {
        x0 = ldv4(ag + 1024); x1 = ldv4(ag + 1028); x2 = ldv4(ag + 1032); x3 = ldv4(ag + 1036);
      }
      if constexpr (AMODE == 2) {
        a2g += 64;
        x0 = ldv4(a2g); x1 = ldv4(a2g + 4); x2 = ldv4(a2g + 8); x3 = ldv4(a2g + 12);
      }
      c0 = ldv4(bg); c1 = ldv4(bg + 4); c2 = ldv4(bg + 8); c3 = ldv4(bg + 12);
    }
#pragma unroll
    for (int kk = 0; kk < 2; ++kk) {
      bf16x8 af[2], bf[2];
#pragma unroll
      for (int mi = 0; mi < 2; ++mi) {
        int row = qr + mi * 16 + c;
        int oct = (kk * 4 + g) ^ (row & 7);
        af[mi] = asbf(*reinterpret_cast<const u16x8*>(As + row * 64 + oct * 8));
      }
#pragma unroll
      for (int ni = 0; ni < 2; ++ni) {
        int row = qc + ni * 16 + c;
        int oct = (kk * 4 + g) ^ (row & 7);
        bf[ni] = asbf(*reinterpret_cast<const u16x8*>(Bs + row * 64 + oct * 8));
      }
#pragma unroll
      for (int mi = 0; mi < 2; ++mi)
#pragma unroll
        for (int ni = 0; ni < 2; ++ni)
          acc[mi][ni] = MFMA16(af[mi], bf[ni], acc[mi][ni]);
    }
  }
#pragma unroll
  for (int mi = 0; mi < 2; ++mi)
#pragma unroll
    for (int ni = 0; ni < 2; ++ni)
#pragma unroll
      for (int r = 0; r < 4; ++r) {
        int row = bm0 + qr + mi * 16 + g * 4 + r;
        int col = bn0 + qc + ni * 16 + c;
        float v = acc[mi][ni][r];
        if constexpr (EPI == 7) {
          if (col < 256) {
            C[(size_t)row * ldc + col] = v;
          } else {
            int cq = col - 256;
            size_t idx = (((size_t)(row >> 4) * 8 + (cq >> 5)) * 64 +
                          ((row >> 2) & 3) * 16 + (cq & 15)) * 8 +
                         ((cq >> 4) & 1) * 4 + (row & 3);
            ((float*)res)[idx] = v;
          }
        } else {
          if constexpr (EPI == 1) v += bscale * bias[col];
          if constexpr (EPI == 2) v = res[(size_t)row * 256 + col] + ada[(row / 384) * 1536 + gate_off + col] * v;
          if constexpr (EPI == 3) v = (res[(size_t)row * 256 + col] + ada[(row / 384) * 1536 + gate_off + col] * v) * mask[row];
          C[(size_t)row * ldc + col] = v;
        }
      }
  if constexpr (EPI == 8) {
    // masked LN partial stats for Q (bn 0..3) / K (bn 4..7) column tiles
    if (bn0 < 512) {
      __shared__ float sred[2][64][2];
#pragma unroll
      for (int mi = 0; mi < 2; ++mi)
#pragma unroll
        for (int r = 0; r < 4; ++r) {
          int lrow = qr + mi * 16 + g * 4 + r;
          float m = mask[bm0 + lrow];
          float ps = 0.f, pss = 0.f;
#pragma unroll
          for (int ni = 0; ni < 2; ++ni) {
            float vv = acc[mi][ni][r] * m;
            ps += vv; pss += vv * vv;
          }
#pragma unroll
          for (int o = 1; o < 16; o <<= 1) { ps += __shfl_xor(ps, o); pss += __shfl_xor(pss, o); }
          if (c == 0) { sred[w & 1][lrow][0] = ps; sred[w & 1][lrow][1] = pss; }
        }
      __syncthreads();
      if (t < 64) {
        float s = sred[0][t][0] + sred[1][t][0];
        float ss = sred[0][t][1] + sred[1][t][1];
        float* st = (float*)res + (size_t)(bm0 + t) * 16 + (bn0 >> 6) * 2;
        st[0] = s; st[1] = ss;
      }
    }
  }
}

// ---------------- edge message kernel (r13 structure + XCD-aware block swizzle):
// 512 thr / 8 waves, SHARED j-chunk in LDS, lane-exact Qx, light barriers.
// blk = (obx&7)*96 + (obx>>3): blocks on the same XCD stream contiguous dist regions.
__global__ __launch_bounds__(512)
void k_edge(const float* __restrict__ dist, const float* __restrict__ emask,
            const float* __restrict__ Wfe1, const float* __restrict__ bfe1,
            const float* __restrict__ P, const float* __restrict__ Qx,
            float* __restrict__ S0, float* __restrict__ S1) {
  const int obx = blockIdx.x, jh = blockIdx.y;
  const int blk = (obx & 7) * 96 + (obx >> 3);  // bijective: 768 = 8*96
  const int b = blk / 384, i = blk - b * 384;
  const int t = threadIdx.x, lane = t & 63, w = t >> 6;  // w in 0..7
  const int g = lane >> 4, c = lane & 15;
  __shared__ __align__(16) unsigned short Al[2][16 * 128];

  // B-fragments: wave w covers h-tiles ht=0,1 at h = w*32 + ht*16 + c
  bf16x8 Bf[2][4];
  float Pl[2], bl[2], Ss[2] = {0.f, 0.f};
#pragma unroll
  for (int ht = 0; ht < 2; ++ht) {
    const int h = w * 32 + ht * 16 + c;
    const float* wp = Wfe1 + (size_t)h * 640 + 512 + g * 8;
#pragma unroll
    for (int ks = 0; ks < 4; ++ks)
      Bf[ht][ks] = pkbf(ldv4(wp + ks * 32), ldv4(wp + ks * 32 + 4));
    Pl[ht] = P[(size_t)(b * 384 + i) * 256 + h];
    bl[ht] = bfe1[h];
  }
  const float* dbase = dist + (size_t)(b * 384 + i) * 49152 + (size_t)jh * 24576;
  const float* embase = emask + (size_t)(b * 384 + i) * 384 + jh * 192;
  const int jcb = b * 24 + jh * 12;
  // lane-exact Q base: per chunk, this lane's 8 floats live contiguously
  const float* qbase = Qx + (((size_t)jcb * 8 + w) * 64 + lane) * 8;

  // staging geometry: thread t covers row=t>>5 (j in chunk), 4 floats at col 4*(t&31)
  const int srow = t >> 5, kq = t & 31;
  const int sunit = kq >> 1;
  const int sphys = (sunit & 8) | ((sunit ^ (srow & 7)) & 7);
  const int soff = srow * 128 + sphys * 8 + (kq & 1) * 4;

  fv4 rX, rY, qvX0, qvX1, qvY0, qvY1, emX, emY;
  // prologue: stage chunk0, prefetch chunk1 + qv/em for chunk0
  {
    fv4 t0 = ldv4(dbase + t * 4);
    *reinterpret_cast<u16x4*>(&Al[0][soff]) = pk4(t0);
  }
  rX = ldv4(dbase + 2048 + t * 4);
  qvX0 = ldv4(qbase);
  qvX1 = ldv4(qbase + 4);
  emX = ldv4(embase + g * 4);
  lbar();

#pragma unroll 1
  for (int p = 0; p < 6; ++p) {
    // ---- iterA: cl = 2p, compute buf0, write buf1 (chunk cl+1 from rX), prefetch into Y
    {
      const int cl = 2 * p;
      if (cl <= 9) rY = ldv4(dbase + (size_t)(cl + 2) * 2048 + t * 4);
      if (cl <= 10) {
        *reinterpret_cast<u16x4*>(&Al[1][soff]) = pk4(rX);
        const float* qp = qbase + (size_t)(cl + 1) * 4096;
        qvY0 = ldv4(qp);
        qvY1 = ldv4(qp + 4);
        emY = ldv4(embase + (cl + 1) * 16 + g * 4);
      }
      fv4 acc0, acc1;
#pragma unroll
      for (int r = 0; r < 4; ++r) { acc0[r] = Pl[0] + qvX0[r]; acc1[r] = Pl[1] + qvX1[r]; }
#pragma unroll
      for (int ks = 0; ks < 4; ++ks) {
        const int u = ks * 4 + g;
        const int phys = (u & 8) | ((u ^ (c & 7)) & 7);
        bf16x8 af = asbf(*reinterpret_cast<const u16x8*>(&Al[0][c * 128 + phys * 8]));
        acc0 = MFMA16(af, Bf[0][ks], acc0);
        acc1 = MFMA16(af, Bf[1][ks], acc1);
      }
#pragma unroll
      for (int r = 0; r < 4; ++r) {
        Ss[0] += siluf(emX[r] * acc0[r] + bl[0]);
        Ss[1] += siluf(emX[r] * acc1[r] + bl[1]);
      }
      lbar();
    }
    // ---- iterB: cl = 2p+1, compute buf1, write buf0 (chunk cl+1 from rY), prefetch into X
    {
      const int cl = 2 * p + 1;
      if (cl <= 9) rX = ldv4(dbase + (size_t)(cl + 2) * 2048 + t * 4);
      if (cl <= 10) {
        *reinterpret_cast<u16x4*>(&Al[0][soff]) = pk4(rY);
        const float* qp = qbase + (size_t)(cl + 1) * 4096;
        qvX0 = ldv4(qp);
        qvX1 = ldv4(qp + 4);
        emX = ldv4(embase + (cl + 1) * 16 + g * 4);
      }
      fv4 acc0, acc1;
#pragma unroll
      for (int r = 0; r < 4; ++r) { acc0[r] = Pl[0] + qvY0[r]; acc1[r] = Pl[1] + qvY1[r]; }
#pragma unroll
      for (int ks = 0; ks < 4; ++ks) {
        const int u = ks * 4 + g;
        const int phys = (u & 8) | ((u ^ (c & 7)) & 7);
        bf16x8 af = asbf(*reinterpret_cast<const u16x8*>(&Al[1][c * 128 + phys * 8]));
        acc0 = MFMA16(af, Bf[0][ks], acc0);
        acc1 = MFMA16(af, Bf[1][ks], acc1);
      }
#pragma unroll
      for (int r = 0; r < 4; ++r) {
        Ss[0] += siluf(emY[r] * acc0[r] + bl[0]);
        Ss[1] += siluf(emY[r] * acc1[r] + bl[1]);
      }
      lbar();
    }
  }
  float* Sp = jh ? S1 : S0;
#pragma unroll
  for (int ht = 0; ht < 2; ++ht) {
    float s = Ss[ht];
    s += __shfl_xor(s, 16);
    s += __shfl_xor(s, 32);
    if (g == 0) Sp[(size_t)(b * 384 + i) * 256 + w * 32 + ht * 16 + c] = s;
  }
}

// ---------------- MFMA attention with fused on-the-fly Q/K LayerNorm.
// Reads raw qkv + per-row LN partial stats (from the qkv GEMM epilogue); normalizes
// Q and K fragments inline. block = 16 q-rows x (b,h); 4 waves split k-range.
__global__ __launch_bounds__(256)
void k_attn(const float* __restrict__ qkv, const float* __restrict__ stats,
            const float* __restrict__ mask, float* __restrict__ ao) {
  const int bh = blockIdx.y, b = bh >> 3, h = bh & 7;
  const int qg = blockIdx.x;
  const int t = threadIdx.x, lane = t & 63, w = t >> 6;
  const int g = lane >> 4, c = lane & 15;
  __shared__ __align__(16) unsigned short Vt[32 * 384];
  __shared__ __align__(16) unsigned short pl[16 * 384];
  __shared__ float outp[4][16][32];
  __shared__ float redm[4][16], reds[4][16];
  __shared__ float kst[384][2];  // mean, rstd per k-row
  // stage V transposed (bf16, swizzled) -- V is raw, unchanged
  {
    const int d0 = (t & 7) * 4;
    const int kp = t >> 3;
#pragma unroll
    for (int pass = 0; pass < 6; ++pass) {
      int k = pass * 64 + kp * 2;
      fv4 v0 = ldv4(qkv + (size_t)(b * 384 + k) * 768 + 512 + h * 32 + d0);
      fv4 v1 = ldv4(qkv + (size_t)(b * 384 + k + 1) * 768 + 512 + h * 32 + d0);
#pragma unroll
      for (int j = 0; j < 4; ++j) {
        int d = d0 + j;
        unsigned int pr = (unsigned int)bfbits(v0[j]) | ((unsigned int)bfbits(v1[j]) << 16);
        *reinterpret_cast<unsigned int*>(&Vt[swz(d, k)]) = pr;
      }
    }
  }
  // K LN stats -> LDS (each row: sum entries 8,10,12,14; sumsq 9,11,13,15)
  for (int idx = t; idx < 384; idx += 256) {
    const float* sp = stats + (size_t)(b * 384 + idx) * 16 + 8;
    fv4 s0 = ldv4(sp), s1 = ldv4(sp + 4);
    float sum = s0[0] + s0[2] + s1[0] + s1[2];
    float ssq = s0[1] + s0[3] + s1[1] + s1[3];
    float mean = sum * (1.f / 256.f);
    kst[idx][0] = mean;
    kst[idx][1] = rsqrtf(ssq * (1.f / 256.f) - mean * mean + 1e-6f);
  }
  // Q fragment: lane c owns q-row qg*16+c; normalize inline
  bf16x8 qf;
  {
    const int qrow = b * 384 + qg * 16 + c;
    const float* sp = stats + (size_t)qrow * 16;
    fv4 s0 = ldv4(sp), s1 = ldv4(sp + 4);
    float sum = s0[0] + s0[2] + s1[0] + s1[2];
    float ssq = s0[1] + s0[3] + s1[1] + s1[3];
    float mq = sum * (1.f / 256.f);
    float rsq = rsqrtf(ssq * (1.f / 256.f) - mq * mq + 1e-6f);
    float qm = mask[qrow];
    const float* qp = qkv + (size_t)qrow * 768 + h * 32 + g * 8;
    fv4 q0 = ldv4(qp), q1 = ldv4(qp + 4);
#pragma unroll
    for (int j = 0; j < 4; ++j) {
      q0[j] = (q0[j] * qm - mq) * rsq;
      q1[j] = (q1[j] * qm - mq) * rsq;
    }
    qf = pkbf(q0, q1);
  }
  __syncthreads();  // kst (and Vt) visible
  // scores: normalize K fragments inline
  fv4 sc[6];
  float kmb[6];
#pragma unroll
  for (int kb = 0; kb < 6; ++kb) {
    const int krow = w * 96 + kb * 16 + c;
    const float km = mask[b * 384 + krow];
    kmb[kb] = km;
    const float kmean = kst[krow][0], krstd = kst[krow][1];
    const float* kp2 = qkv + (size_t)(b * 384 + krow) * 768 + 256 + h * 32 + g * 8;
    fv4 k0 = ldv4(kp2), k1 = ldv4(kp2 + 4);
#pragma unroll
    for (int j = 0; j < 4; ++j) {
      k0[j] = (k0[j] * km - kmean) * krstd;
      k1[j] = (k1[j] * km - kmean) * krstd;
    }
    bf16x8 kf = pkbf(k0, k1);
    fv4 z = {0.f, 0.f, 0.f, 0.f};
    sc[kb] = MFMA16(qf, kf, z);
  }
  const float rs = 0.1767766952966369f;
  float zz[6][4], mx[4] = {-3e38f, -3e38f, -3e38f, -3e38f};
#pragma unroll
  for (int kb = 0; kb < 6; ++kb) {
    float mb = kmb[kb] > 0.f ? 0.f : -1e9f;
#pragma unroll
    for (int r = 0; r < 4; ++r) {
      zz[kb][r] = sc[kb][r] * rs + mb;
      mx[r] = fmaxf(mx[r], zz[kb][r]);
    }
  }
#pragma unroll
  for (int r = 0; r < 4; ++r) {
#pragma unroll
    for (int o = 1; o < 16; o <<= 1) mx[r] = fmaxf(mx[r], __shfl_xor(mx[r], o));
  }
  if (c == 0) {
#pragma unroll
    for (int r = 0; r < 4; ++r) redm[w][g * 4 + r] = mx[r];
  }
  __syncthreads();
  float m4[4], sm[4] = {0.f, 0.f, 0.f, 0.f};
#pragma unroll
  for (int r = 0; r < 4; ++r) {
    int q = g * 4 + r;
    m4[r] = fmaxf(fmaxf(redm[0][q], redm[1][q]), fmaxf(redm[2][q], redm[3][q]));
  }
#pragma unroll
  for (int kb = 0; kb < 6; ++kb) {
    int k = w * 96 + kb * 16 + c;
#pragma unroll
    for (int r = 0; r < 4; ++r) {
      float p = __builtin_amdgcn_exp2f((zz[kb][r] - m4[r]) * 1.44269504f);
      sm[r] += p;
      pl[swz(g * 4 + r, k)] = bfbits(p);
    }
  }
#pragma unroll
  for (int r = 0; r < 4; ++r) {
#pragma unroll
    for (int o = 1; o < 16; o <<= 1) sm[r] += __shfl_xor(sm[r], o);
  }
  if (c == 0) {
#pragma unroll
    for (int r = 0; r < 4; ++r) reds[w][g * 4 + r] = sm[r];
  }
  __syncthreads();
  fv4 oacc[2] = {};
#pragma unroll
  for (int kk = 0; kk < 3; ++kk) {
    int kbase = w * 96 + kk * 32 + g * 8;
    bf16x8 pa = asbf(*reinterpret_cast<const u16x8*>(&pl[swz(c, kbase)]));
#pragma unroll
    for (int db = 0; db < 2; ++db) {
      int d = db * 16 + c;
      bf16x8 vb = asbf(*reinterpret_cast<const u16x8*>(&Vt[swz(d, kbase)]));
      oacc[db] = MFMA16(pa, vb, oacc[db]);
    }
  }
#pragma unroll
  for (int db = 0; db < 2; ++db)
#pragma unroll
    for (int r = 0; r < 4; ++r) outp[w][g * 4 + r][db * 16 + c] = oacc[db][r];
  __syncthreads();
#pragma unroll
  for (int idx = t; idx < 512; idx += 256) {
    int q = idx >> 5, d = idx & 31;
    float v = outp[0][q][d] + outp[1][q][d] + outp[2][q][d] + outp[3][q][d];
    float s = reds[0][q] + reds[1][q] + reds[2][q] + reds[3][q];
    ao[(size_t)(b * 384 + qg * 16 + q) * 256 + h * 32 + d] = v / s;
  }
}

extern "C" void kernel_launch(void* const* d_in, const int* in_sizes, int n_in,
                              void* d_out, int out_size, void* d_ws, size_t ws_size,
                              hipStream_t stream) {
  (void)in_sizes; (void)n_in; (void)out_size; (void)ws_size;
  const float* mask   = (const float*)d_in[0];
  const float* x      = (const float*)d_in[1];
  const float* temb   = (const float*)d_in[2];
  const float* dist   = (const float*)d_in[3];
  const float* emask  = (const float*)d_in[4];
  const float* W_ada  = (const float*)d_in[5];
  const float* b_ada  = (const float*)d_in[6];
  const float* W_fe1  = (const float*)d_in[7];
  const float* b_fe1  = (const float*)d_in[8];
  const float* W_fe2  = (const float*)d_in[9];
  const float* b_fe2  = (const float*)d_in[10];
  const float* W_qkv  = (const float*)d_in[11];
  const float* W_out  = (const float*)d_in[12];
  const float* W_ffn1 = (const float*)d_in[13];
  const float* W_ffn2 = (const float*)d_in[14];
  float* out = (float*)d_out;
  float* ws = (float*)d_ws;

  float* ada   = ws;              // 3072
  float* xattn = ws + 4096;       // 196608
  float* xm    = ws + 200704;     // 196608
  float* xn    = ws + 397312;     // 196608
  float* P     = ws + 593920;     // 196608
  float* Qx    = ws + 790528;     // 196608 (lane-exact: [(chunk*8+w)*64+lane][8])
  float* S0    = ws + 987136;     // 196608 (j-half 0 partial)
  float* xmsg  = ws + 1183744;    // 196608
  float* qkvb  = ws + 1380352;    // 589824
  float* stats = ws + 1970176;    // 12288 (LN partial stats [row][16])
  float* aob   = ws + 2166784;    // 196608
  float* S1    = ws + 2363392;    // j-half 1 partial
  float* h12   = ws + 397312;     // 1572864, aliases xn..qkvb (dead by then)

  k_ada<<<12, 256, 0, stream>>>(temb, W_ada, b_ada, ada);
  k_xnorm<<<768, 256, 0, stream>>>(x, mask, ada, 0, 256, xn);
  // merged: P (cols 0..255) + Qx (cols 256..511, lane-exact via res) in one launch
  k_gemm<7, 0><<<dim3(8, 12), 256, 0, stream>>>(xn, 256, W_fe1, 640, 0, 256, P, 256,
                                                nullptr, 0.f, Qx, nullptr, 0, nullptr);
  k_edge<<<dim3(768, 2), 512, 0, stream>>>(dist, emask, W_fe1, b_fe1, P, Qx, S0, S1);
  // x_msg = (S0+S1) @ W_fe2^T + 384*b_fe2   (AMODE=2 adds res=S1 rows into A)
  k_gemm<1, 2><<<dim3(4, 12), 256, 0, stream>>>(S0, 256, W_fe2, 256, 0, 256, xmsg, 256,
                                                b_fe2, 384.f, S1, nullptr, 0, nullptr);
  // qkv GEMM + masked LN partial stats into `stats` (res slot)
  k_gemm<8, 0><<<dim3(12, 12), 256, 0, stream>>>(xmsg, 256, W_qkv, 256, 0, 256, qkvb, 768,
                                                 nullptr, 0.f, stats, nullptr, 0, mask);
  k_attn<<<dim3(24, 16), 256, 0, stream>>>(qkvb, stats, mask, aob);
  k_gemm<2, 0><<<dim3(4, 12), 256, 0, stream>>>(aob, 256, W_out, 256, 0, 256, xattn, 256,
                                                nullptr, 0.f, x, ada, 512, nullptr);
  k_xnorm<<<768, 256, 0, stream>>>(xattn, mask, ada, 768, 1024, xm);
  k_gemm<0, 0><<<dim3(32, 12), 256, 0, stream>>>(xm, 256, W_ffn1, 256, 0, 256, h12, 2048,
                                                 nullptr, 0.f, nullptr, nullptr, 0, nullptr);
  k_gemm<3, 1><<<dim3(4, 12), 256, 0, stream>>>(h12, 2048, W_ffn2, 1024, 0, 1024, out, 256,
                                                nullptr, 0.f, xattn, ada, 1280, mask);
}